// Round 2
// baseline (4027.449 us; speedup 1.0000x reference)
//
#include <hip/hip_runtime.h>
#include <hip/hip_bf16.h>
#include <stdint.h>

typedef __bf16 bf16x8 __attribute__((ext_vector_type(8)));
typedef short  short8 __attribute__((ext_vector_type(8)));
typedef float  f32x4  __attribute__((ext_vector_type(4)));

__device__ __forceinline__ unsigned short f2bf(float x) {
  unsigned u = __builtin_bit_cast(unsigned, x);
  u = (u + 0x7FFFu + ((u >> 16) & 1u)) >> 16;
  return (unsigned short)u;
}

// ---------------- K1: emb + weight pre-packing ----------------
__global__ __launch_bounds__(256) void k1_prep(
    const float* __restrict__ phr, const float* __restrict__ Wp,
    const float* __restrict__ bp, const float* __restrict__ Wc,
    const float* __restrict__ Wih, const float* __restrict__ bih,
    const float* __restrict__ bhh, float* __restrict__ emb,
    unsigned short* __restrict__ Wtf, unsigned short* __restrict__ Bf2,
    float* __restrict__ bsum) {
  int tid = threadIdx.x, blk = blockIdx.x;
  if (blk < 16) {                       // phrase embed (64 x 64)
    int gid = blk * 256 + tid; int b = gid >> 6, f = gid & 63;
    float acc = bp[f];
    for (int k = 0; k < 300; ++k) acc += phr[b * 300 + k] * Wp[k * 64 + f];
    emb[gid] = fmaxf(acc, 0.f);
  } else if (blk < 48) {                // k2 B-fragments: 50x4x2 frags x 64 lanes
    for (int sid = (blk - 16) * 256 + tid; sid < 25600; sid += 8192) {
      int lane = sid & 63, f = sid >> 6;
      int kk = f & 1, ct = (f >> 1) & 3, c = f >> 3;
      int col = ct * 16 + (lane & 15);
      int k = c * 64 + kk * 32 + (lane >> 4) * 8;
      short8 v;
#pragma unroll
      for (int j = 0; j < 8; ++j) v[j] = (short)f2bf(Wc[(k + j) * 64 + col]);
      *(short8*)(Wtf + (size_t)sid * 8) = v;
    }
  } else if (blk < 80) {                // k2b B-fragments: 64x2 frags x 64 lanes
    int sid = (blk - 48) * 256 + tid;
    int lane = sid & 63, f = sid >> 6;
    int kk = f & 1, ct = f >> 1;
    int col = ct * 16 + (lane & 15);
    int k = kk * 32 + (lane >> 4) * 8;
    short8 v;
#pragma unroll
    for (int j = 0; j < 8; ++j) v[j] = (short)f2bf(Wih[(k + j) * 1024 + col]);
    *(short8*)(Bf2 + (size_t)sid * 8) = v;
  } else if (blk < 84) {                // bias sum
    int c = (blk - 80) * 256 + tid;
    bsum[c] = bih[c] + bhh[c];
  }
}

// ---------------- K2: img_fc + fuse via MFMA (HBM-bound) ----------------
__global__ __launch_bounds__(256) void k2_imgfuse(
    const float* __restrict__ img, const float* __restrict__ bc,
    const float* __restrict__ emb, const unsigned short* __restrict__ Wtf,
    unsigned short* __restrict__ fuse) {
  __shared__ __align__(16) unsigned short sA[64 * 72];  // 64 rows x 64k bf16, +8 pad
  int tid = threadIdx.x, blk = blockIdx.x;
  int lane = tid & 63, w = tid >> 6, q = lane >> 4, c16 = lane & 15;
  int R0 = blk * 64;
  int srow = tid >> 2, scq = tid & 3;
  const float* srcbase = img + (size_t)(R0 + srow) * 3200 + scq * 16;
  f32x4 acc[4] = {};
  for (int c = 0; c < 50; ++c) {
    const float4* s4 = (const float4*)(srcbase + c * 64);
    float4 v0 = s4[0], v1 = s4[1], v2 = s4[2], v3 = s4[3];
    short8 p0, p1;
    p0[0] = (short)f2bf(v0.x); p0[1] = (short)f2bf(v0.y);
    p0[2] = (short)f2bf(v0.z); p0[3] = (short)f2bf(v0.w);
    p0[4] = (short)f2bf(v1.x); p0[5] = (short)f2bf(v1.y);
    p0[6] = (short)f2bf(v1.z); p0[7] = (short)f2bf(v1.w);
    p1[0] = (short)f2bf(v2.x); p1[1] = (short)f2bf(v2.y);
    p1[2] = (short)f2bf(v2.z); p1[3] = (short)f2bf(v2.w);
    p1[4] = (short)f2bf(v3.x); p1[5] = (short)f2bf(v3.y);
    p1[6] = (short)f2bf(v3.z); p1[7] = (short)f2bf(v3.w);
    *(short8*)(sA + srow * 72 + scq * 16) = p0;
    *(short8*)(sA + srow * 72 + scq * 16 + 8) = p1;
    __syncthreads();
    bf16x8 a0 = *(const bf16x8*)(sA + (w * 16 + c16) * 72 + q * 8);
    bf16x8 a1 = *(const bf16x8*)(sA + (w * 16 + c16) * 72 + 32 + q * 8);
#pragma unroll
    for (int ct = 0; ct < 4; ++ct) {
      bf16x8 b0 = *(const bf16x8*)(Wtf + (size_t)(((c * 4 + ct) * 2 + 0) * 64 + lane) * 8);
      bf16x8 b1 = *(const bf16x8*)(Wtf + (size_t)(((c * 4 + ct) * 2 + 1) * 64 + lane) * 8);
      acc[ct] = __builtin_amdgcn_mfma_f32_16x16x32_bf16(a0, b0, acc[ct], 0, 0, 0);
      acc[ct] = __builtin_amdgcn_mfma_f32_16x16x32_bf16(a1, b1, acc[ct], 0, 0, 0);
    }
    __syncthreads();
  }
  int bidx = R0 >> 9;  // 64-row block never straddles a batch (512 % 64 == 0)
#pragma unroll
  for (int ct = 0; ct < 4; ++ct) {
    int col = ct * 16 + c16;
    float bcv = bc[col], ev = emb[bidx * 64 + col];
#pragma unroll
    for (int r = 0; r < 4; ++r) {
      int rowg = R0 + w * 16 + q * 4 + r;
      float v = fmaxf(acc[ct][r] + bcv, 0.f) * ev;
      fuse[(size_t)rowg * 64 + col] = f2bf(v);
    }
  }
}

// ---------------- K2b: gates_x = fuse @ W_ih + b, pre-swizzled f32 ----------------
__global__ __launch_bounds__(256) void k2b_gatesx(
    const unsigned short* __restrict__ fuse, const unsigned short* __restrict__ Bf2,
    const float* __restrict__ bsum, float* __restrict__ gx) {
  int tid = threadIdx.x, blk = blockIdx.x;
  int lane = tid & 63, w = tid >> 6, q = lane >> 4, c16 = lane & 15;
  int wid = blk * 4 + w;          // tile id: (group, step)
  int g = wid >> 9, s = wid & 511;
  const unsigned short* abase = fuse + ((size_t)(g * 16 + c16) * 512 + s) * 64;
  bf16x8 a0 = *(const bf16x8*)(abase + q * 8);
  bf16x8 a1 = *(const bf16x8*)(abase + 32 + q * 8);
  float* gbase = gx + (size_t)(g * 512 + s) * 16384;
#pragma unroll 4
  for (int ct = 0; ct < 64; ++ct) {
    f32x4 acc = {};
    bf16x8 b0 = *(const bf16x8*)(Bf2 + (size_t)((ct * 2 + 0) * 64 + lane) * 8);
    bf16x8 b1 = *(const bf16x8*)(Bf2 + (size_t)((ct * 2 + 1) * 64 + lane) * 8);
    acc = __builtin_amdgcn_mfma_f32_16x16x32_bf16(a0, b0, acc, 0, 0, 0);
    acc = __builtin_amdgcn_mfma_f32_16x16x32_bf16(a1, b1, acc, 0, 0, 0);
    float bs = bsum[ct * 16 + c16];
    int T = (ct >> 4) * 4 + (ct & 3);
    int w3 = (ct >> 2) & 3;
    float2 lo; lo.x = acc[0] + bs; lo.y = acc[1] + bs;
    float2 hi; hi.x = acc[2] + bs; hi.y = acc[3] + bs;
    float* dst = gbase + w3 * 4096 + T * 256 + lane * 2;
    *(float2*)(dst) = lo;
    *(float2*)(dst + 128) = hi;
  }
}

// ---------------- K3: LSTM, one WG per batch group, weights in regs+LDS ----------------
__global__ __launch_bounds__(256, 1) void k3_lstm(
    const float* __restrict__ Whh, const float* __restrict__ gx,
    float* __restrict__ outfeats) {
  __shared__ __align__(16) unsigned short ldsB[16 * 16 * 264];  // 4w x 4tt x 16c x 264
  __shared__ __align__(16) unsigned short hA[2][16 * 264];
  int tid = threadIdx.x;
  int g = blockIdx.x;
  int lane = tid & 63, w = tid >> 6, q = lane >> 4, c16 = lane & 15;

  // --- stage 12 register tiles (gates i,f,g): col = gate*256 + w*64 + usub*16 + c16
  bf16x8 Br[12][8];
  {
    const float* pb = Whh + q * 8192 + w * 64 + c16;
#pragma unroll
    for (int t = 0; t < 12; ++t) {
      int colofs = (t >> 2) * 256 + (t & 3) * 16;
#pragma unroll
      for (int kk = 0; kk < 8; ++kk) {
        const float* p = pb + colofs + kk * 32768;
        short8 v;
#pragma unroll
        for (int j = 0; j < 8; ++j) v[j] = (short)f2bf(p[j * 1024]);
        Br[t][kk] = __builtin_bit_cast(bf16x8, v);
      }
    }
  }
  // --- stage gate-o tiles into LDS (cols 768 + w*64 + lane, all 256 k)
  {
    unsigned elem = (unsigned)((w * 4 + q) * 16 + c16) * 264;
    const float* ps = Whh + 768 + w * 64 + lane;
    for (int k = 0; k < 256; k += 2) {
      unsigned pk = (unsigned)f2bf(ps[k * 1024]) |
                    ((unsigned)f2bf(ps[(k + 1) * 1024]) << 16);
      *(unsigned*)(ldsB + elem + k) = pk;
    }
  }
  for (int i = tid; i < 16 * 264; i += 256) hA[1][i] = 0;

  float c[16];
#pragma unroll
  for (int i = 0; i < 16; ++i) c[i] = 0.f;

  f32x4 acc[16];
  const float* gxw = gx + (size_t)(g * 2048 + w) * 4096 + lane * 2;
#pragma unroll
  for (int T = 0; T < 16; ++T) {   // preload gx[s=0] into acc
    float2 lo = *(const float2*)(gxw + T * 256);
    float2 hi = *(const float2*)(gxw + T * 256 + 128);
    f32x4 a; a[0] = lo.x; a[1] = lo.y; a[2] = hi.x; a[3] = hi.y;
    acc[T] = a;
  }
  __syncthreads();

  const unsigned short* bl_base = ldsB + (unsigned)(w * 4 * 16 + c16) * 264 + q * 8;
  float* outb = outfeats + (size_t)(g * 16) * 512 * 256 + w * 64;

  for (int s = 0; s < 512; ++s) {
    const unsigned short* ha = &hA[(s + 1) & 1][c16 * 264 + q * 8];
#pragma unroll
    for (int kk = 0; kk < 8; ++kk) {
      bf16x8 a = *(const bf16x8*)(ha + kk * 32);
#pragma unroll
      for (int t = 0; t < 12; ++t)
        acc[t] = __builtin_amdgcn_mfma_f32_16x16x32_bf16(a, Br[t][kk], acc[t], 0, 0, 0);
#pragma unroll
      for (int tt = 0; tt < 4; ++tt) {
        bf16x8 b = *(const bf16x8*)(bl_base + tt * 4224 + kk * 32);
        acc[12 + tt] = __builtin_amdgcn_mfma_f32_16x16x32_bf16(a, b, acc[12 + tt], 0, 0, 0);
      }
    }
    // pointwise (i,f,g,o = acc[su], acc[4+su], acc[8+su], acc[12+su])
    unsigned short* hw = &hA[s & 1][0];
    float* outs = outb + (size_t)s * 256 + c16;
#pragma unroll
    for (int su = 0; su < 4; ++su) {
#pragma unroll
      for (int r = 0; r < 4; ++r) {
        float gi = acc[su][r], gf = acc[4 + su][r];
        float gg = acc[8 + su][r], go = acc[12 + su][r];
        float si = 1.f / (1.f + __expf(-gi));
        float sf = 1.f / (1.f + __expf(-gf));
        float so = 1.f / (1.f + __expf(-go));
        float e2g = __expf(2.f * gg);
        float tg = (e2g - 1.f) / (e2g + 1.f);
        float cn = sf * c[su * 4 + r] + si * tg;
        c[su * 4 + r] = cn;
        float e2c = __expf(2.f * cn);
        float hn = so * (e2c - 1.f) / (e2c + 1.f);
        int m = q * 4 + r;
        outs[(size_t)m * 131072 + su * 16] = hn;
        hw[m * 264 + w * 64 + su * 16 + c16] = f2bf(hn);
      }
    }
    // refill acc with gx[s+1] (wrap at end; last refill unused)
    {
      int sn = (s + 1) & 511;
      const float* gp = gxw + (size_t)sn * 16384;
#pragma unroll
      for (int T = 0; T < 16; ++T) {
        float2 lo = *(const float2*)(gp + T * 256);
        float2 hi = *(const float2*)(gp + T * 256 + 128);
        f32x4 a; a[0] = lo.x; a[1] = lo.y; a[2] = hi.x; a[3] = hi.y;
        acc[T] = a;
      }
    }
    __syncthreads();
  }
}

// ---------------- K4: classifier + log_softmax ----------------
__global__ __launch_bounds__(256) void k4_classifier(
    const float* __restrict__ feats, const float* __restrict__ Wc1,
    const float* __restrict__ bc1, const float* __restrict__ Wc2,
    const float* __restrict__ bc2, float* __restrict__ lp) {
  __shared__ float sW[64 * 64];
  __shared__ float sX[16 * 257];
  __shared__ float sH[16 * 68];
  int tid = threadIdx.x, blk = blockIdx.x;
  {
    int rs = tid >> 4, seg = (tid & 15) * 16;
    const float4* src = (const float4*)(feats + (size_t)(blk * 16 + rs) * 256 + seg);
    float* xd = sX + rs * 257 + seg;
#pragma unroll
    for (int i = 0; i < 4; ++i) {
      float4 v = src[i];
      xd[i*4+0]=v.x; xd[i*4+1]=v.y; xd[i*4+2]=v.z; xd[i*4+3]=v.w;
    }
  }
  int r = tid & 15, g = tid >> 4;
  float acc[4] = {0.f, 0.f, 0.f, 0.f};
  for (int c4 = 0; c4 < 4; ++c4) {
    __syncthreads();
#pragma unroll
    for (int i = 0; i < 4; ++i)
      ((float4*)sW)[i * 256 + tid] = ((const float4*)(Wc1 + c4 * 4096))[i * 256 + tid];
    __syncthreads();
#pragma unroll 8
    for (int k = 0; k < 64; ++k) {
      float xv = sX[r * 257 + c4 * 64 + k];
      float4 wv = *(const float4*)(sW + k * 64 + g * 4);
      acc[0] += xv * wv.x; acc[1] += xv * wv.y; acc[2] += xv * wv.z; acc[3] += xv * wv.w;
    }
  }
#pragma unroll
  for (int j = 0; j < 4; ++j) {
    int c = g * 4 + j;
    sH[r * 68 + c] = fmaxf(acc[j] + bc1[c], 0.f);
  }
  __syncthreads();
  if (tid < 16) {
    float l0 = bc2[0], l1 = bc2[1];
    for (int c = 0; c < 64; ++c) {
      float h = sH[tid * 68 + c];
      l0 += h * Wc2[c * 2]; l1 += h * Wc2[c * 2 + 1];
    }
    float mx = fmaxf(l0, l1);
    float lse = mx + logf(__expf(l0 - mx) + __expf(l1 - mx));
    int rowg = blk * 16 + tid;
    lp[rowg * 2]     = l0 - lse;
    lp[rowg * 2 + 1] = l1 - lse;
  }
}

// ---------------- K5: gather selected ----------------
__global__ __launch_bounds__(256) void k5_select(
    const float* __restrict__ feats, const int* __restrict__ six,
    float* __restrict__ sel) {
  int b = blockIdx.x, tid = threadIdx.x;
  int ix = six[b];
  sel[b * 256 + tid] = feats[((size_t)b * 512 + ix) * 256 + tid];
}

extern "C" void kernel_launch(void* const* d_in, const int* in_sizes, int n_in,
                              void* d_out, int out_size, void* d_ws, size_t ws_size,
                              hipStream_t stream) {
  const float* img = (const float*)d_in[0];
  const float* phr = (const float*)d_in[1];
  const int*   six = (const int*)d_in[3];
  const float* Wc  = (const float*)d_in[4];
  const float* bc  = (const float*)d_in[5];
  const float* Wp  = (const float*)d_in[6];
  const float* bp  = (const float*)d_in[7];
  const float* Wih = (const float*)d_in[8];
  const float* bih = (const float*)d_in[9];
  const float* Whh = (const float*)d_in[10];
  const float* bhh = (const float*)d_in[11];
  const float* Wc1 = (const float*)d_in[12];
  const float* bc1 = (const float*)d_in[13];
  const float* Wc2 = (const float*)d_in[14];
  const float* bc2 = (const float*)d_in[15];

  float* out_lp   = (float*)d_out;        // (64,512,2)
  float* out_feat = out_lp + 65536;       // (64,512,256)
  float* out_sel  = out_feat + 8388608;   // (64,256)

  char* ws = (char*)d_ws;
  float*          emb  = (float*)ws;                         // 16 KB
  unsigned short* fuse = (unsigned short*)(ws + 16384);      // 4 MB
  unsigned short* Wtf  = (unsigned short*)(ws + 4210688);    // 400 KB
  unsigned short* Bf2  = (unsigned short*)(ws + 4620288);    // 256 KB
  float*          bsum = (float*)(ws + 4882432);             // 4 KB
  float*          gx   = (float*)(ws + 4886528);             // 128 MB

  hipLaunchKernelGGL(k1_prep, dim3(84), dim3(256), 0, stream,
                     phr, Wp, bp, Wc, Wih, bih, bhh, emb, Wtf, Bf2, bsum);
  hipLaunchKernelGGL(k2_imgfuse, dim3(512), dim3(256), 0, stream,
                     img, bc, emb, Wtf, fuse);
  hipLaunchKernelGGL(k2b_gatesx, dim3(512), dim3(256), 0, stream,
                     fuse, Bf2, bsum, gx);
  hipLaunchKernelGGL(k3_lstm, dim3(4), dim3(256), 0, stream,
                     Whh, gx, out_feat);
  hipLaunchKernelGGL(k4_classifier, dim3(2048), dim3(256), 0, stream,
                     out_feat, Wc1, bc1, Wc2, bc2, out_lp);
  hipLaunchKernelGGL(k5_select, dim3(64), dim3(256), 0, stream,
                     out_feat, six, out_sel);
}